// Round 5
// baseline (489.375 us; speedup 1.0000x reference)
//
#include <hip/hip_runtime.h>
#include <hip/hip_bf16.h>

// BiPairwiseNegativeCELoss on MI355X.
// Inputs: q, d, nd : [16384, 128] fp32. Output: scalar fp32 loss.
// loss = 0.5 * ( mean(softplus(q.nd_row - q.d_row))
//              + mean(softplus(max_c(q_b . d_c, diag -1e6) - q_b.d_b)) )
//
// R5: (a) inbatch: 512 blocks (32 rg x 16 cg), 2 blocks/CU (64 KB LDS each),
//     4 waves/SIMD -- cross-block overlap hides barrier/ds_read stalls.
//     (b) prep: 2048 blocks, full occupancy, no serial loop.
//     (c) all reductions via partial arrays: no atomics, no memset node.

#define BATCH 16384
#define DDIM  128
#define NWAVES 8                 // 512 threads
#define ROWS_PER_BLOCK 512       // 8 waves x 64 rows
#define COLS_PER_BLOCK 1024      // 16 col-groups
#define CHUNK_COLS 128           // 32 KB bf16 per chunk
#define NCHUNKS (COLS_PER_BLOCK / CHUNK_COLS)   // 8
#define CHUNK_USHORTS (CHUNK_COLS * DDIM)       // 16384
#define NCG (BATCH / COLS_PER_BLOCK)            // 16
#define NPREP 2048                               // prep blocks (8 rows each)
#define NRED  64                                 // reduce blocks

typedef __attribute__((ext_vector_type(8))) short bf16x8;   // 8 bf16 = 4 VGPRs
typedef __attribute__((ext_vector_type(4))) float f32x4;

__device__ __forceinline__ float softplus_f(float x) {
    return (x > 0.0f) ? x + log1pf(expf(-x)) : log1pf(expf(x));
}

__device__ __forceinline__ ushort f2bf_rne(float x) {
    unsigned u = __float_as_uint(x);
    unsigned r = (u + 0x7FFFu + ((u >> 16) & 1u)) >> 16;
    return (ushort)r;
}

#define WAITVM(n) do { \
        __builtin_amdgcn_s_waitcnt((n) | (7 << 4) | (15 << 8)); \
        asm volatile("" ::: "memory"); \
    } while (0)

// ---------------------------------------------------------------------------
// Kernel A: pairwise dots (fp32 exact), loss1 block partials, bf16 casts.
// 2048 blocks x 256 threads (8 blocks/CU -> 32 waves/CU). Block owns 8 rows;
// 32 threads per row, one float4 per thread per stream. No atomics.
// ---------------------------------------------------------------------------
__global__ __launch_bounds__(256) void prep_kernel(
    const float* __restrict__ q, const float* __restrict__ d,
    const float* __restrict__ nd,
    ushort* __restrict__ qb, ushort* __restrict__ db,
    float* __restrict__ pos, float* __restrict__ loss1_part)
{
    const int t   = threadIdx.x;
    const int sub = t >> 5;                      // row 0..7 within block
    const int ln  = t & 31;                      // 32 threads per row
    const int row = blockIdx.x * 8 + sub;
    const size_t idx = (size_t)row * DDIM + ln * 4;

    float4 a = *(const float4*)(q  + idx);
    float4 b = *(const float4*)(d  + idx);
    float4 c = *(const float4*)(nd + idx);

    ushort4 o;
    o.x = f2bf_rne(a.x); o.y = f2bf_rne(a.y);
    o.z = f2bf_rne(a.z); o.w = f2bf_rne(a.w);
    *(ushort4*)(qb + idx) = o;
    ushort4 p;
    p.x = f2bf_rne(b.x); p.y = f2bf_rne(b.y);
    p.z = f2bf_rne(b.z); p.w = f2bf_rne(b.w);
    *(ushort4*)(db + idx) = p;

    float ps = a.x * b.x + a.y * b.y + a.z * b.z + a.w * b.w;
    float ns = a.x * c.x + a.y * c.y + a.z * c.z + a.w * c.w;
    ps += __shfl_xor(ps, 1); ps += __shfl_xor(ps, 2);
    ps += __shfl_xor(ps, 4); ps += __shfl_xor(ps, 8);
    ps += __shfl_xor(ps, 16);
    ns += __shfl_xor(ns, 1); ns += __shfl_xor(ns, 2);
    ns += __shfl_xor(ns, 4); ns += __shfl_xor(ns, 8);
    ns += __shfl_xor(ns, 16);

    float contrib = 0.0f;
    if (ln == 0) {
        pos[row] = ps;                     // == scores[b][b], exact fp32
        contrib = softplus_f(ns - ps);
    }
    contrib += __shfl_xor(contrib, 32);    // combine the wave's two rows

    __shared__ float red[4];
    if ((t & 63) == 0) red[t >> 6] = contrib;
    __syncthreads();
    if (t == 0)
        loss1_part[blockIdx.x] = red[0] + red[1] + red[2] + red[3];
}

// ---------------------------------------------------------------------------
// Kernel B: fused GEMM + row-max. 512 blocks x 512 threads, 2 blocks/CU.
// Block (rg = bx&31, cg = bx>>5): rows [rg*512, +512), cols [cg*1024, +1024).
// Wave w owns 64 rows (A in registers, whole K). B staged cooperatively:
// 128-col chunks, 2x32KB LDS double buffer, XOR-swizzled 16B k-segments
// (swizzle on the GLOBAL address; LDS dest of global_load_lds is lane-linear:
// LDS slot s of col c holds global segment s ^ (c&15)).
// ---------------------------------------------------------------------------
__global__ __launch_bounds__(512, 4) void inbatch_kernel(
    const ushort* __restrict__ qb, const ushort* __restrict__ db,
    float* __restrict__ partials)
{
    __shared__ ushort stg[2][CHUNK_USHORTS];   // 2 x 32 KB

    const int t      = threadIdx.x;
    const int w      = t >> 6;
    const int l      = t & 63;
    const int lane16 = l & 15;
    const int quad   = l >> 4;
    const int rg     = blockIdx.x & 31;
    const int cg     = blockIdx.x >> 5;
    const int rows0  = rg * ROWS_PER_BLOCK + w * 64;   // this wave's 64 rows
    const int col0   = cg * COLS_PER_BLOCK;

    // A fragments: lane l holds Q[rows0 + rs*16 + (l&15)][ks*32 + quad*8 + j]
    bf16x8 afrag[4][4];
#pragma unroll
    for (int rs = 0; rs < 4; ++rs)
#pragma unroll
        for (int ks = 0; ks < 4; ++ks)
            afrag[rs][ks] = *(const bf16x8*)(
                qb + (size_t)(rows0 + rs * 16 + lane16) * DDIM + ks * 32 + quad * 8);

    // staging: thread t handles 16B segments i*512 + t (i = 0..3) of each
    // chunk; seg -> col = seg>>4, LDS slot = seg&15, global kseg = slot^(col&15)
    const ushort* gsrc[4];
#pragma unroll
    for (int i = 0; i < 4; ++i) {
        int seg = i * 512 + t;
        int c   = seg >> 4;
        int s   = seg & 15;
        gsrc[i] = db + (size_t)(col0 + c) * DDIM + ((s ^ (c & 15)) * 8);
    }

    // ds_read base (ushort offsets); per-(ct,buf) selected by immediate offset
    int dsbase[4];
#pragma unroll
    for (int ks = 0; ks < 4; ++ks)
        dsbase[ks] = lane16 * DDIM + (((ks * 4 + quad) ^ lane16) * 8);

    float runmax[4][4];
#pragma unroll
    for (int rs = 0; rs < 4; ++rs)
#pragma unroll
        for (int r = 0; r < 4; ++r) runmax[rs][r] = -3.0e38f;

    // prologue: stage chunk 0 into buf 0 (LDS dest wave-uniform + lane*16B)
#pragma unroll
    for (int i = 0; i < 4; ++i)
        __builtin_amdgcn_global_load_lds(
            (const __attribute__((address_space(1))) void*)gsrc[i],
            (__attribute__((address_space(3))) void*)(&stg[0][0] + (i * 512 + w * 64) * 8),
            16, 0, 0);

    for (int ch = 0; ch < NCHUNKS; ++ch) {
        WAITVM(0);
        __syncthreads();                     // chunk ch visible; buf ch^1 free
        if (ch + 1 < NCHUNKS) {              // prefetch next chunk now; it has
#pragma unroll                               // the whole compute phase to land
            for (int i = 0; i < 4; ++i)
                __builtin_amdgcn_global_load_lds(
                    (const __attribute__((address_space(1))) void*)(gsrc[i] + (size_t)(ch + 1) * CHUNK_USHORTS),
                    (__attribute__((address_space(3))) void*)(&stg[(ch + 1) & 1][0] + (i * 512 + w * 64) * 8),
                    16, 0, 0);
        }

        const ushort* buf = &stg[ch & 1][0];
#pragma unroll
        for (int ct = 0; ct < 8; ++ct) {
            bf16x8 bfrag[4];
#pragma unroll
            for (int ks = 0; ks < 4; ++ks)
                bfrag[ks] = *(const bf16x8*)(buf + dsbase[ks] + ct * 2048);

            const int ctile = col0 + ch * CHUNK_COLS + ct * 16;
#pragma unroll
            for (int rs = 0; rs < 4; ++rs) {
                f32x4 s = {0.0f, 0.0f, 0.0f, 0.0f};
#pragma unroll
                for (int ks = 0; ks < 4; ++ks)
                    s = __builtin_amdgcn_mfma_f32_16x16x32_bf16(
                        afrag[rs][ks], bfrag[ks], s, 0, 0, 0);
                if (ctile == rows0 + rs * 16) {    // diagonal tile: -1e6
#pragma unroll
                    for (int r = 0; r < 4; ++r)
                        if (quad * 4 + r == lane16) s[r] -= 1.0e6f;
                }
#pragma unroll
                for (int r = 0; r < 4; ++r)
                    runmax[rs][r] = fmaxf(runmax[rs][r], s[r]);
            }
        }
    }

    // reduce max across the 16 lanes (cols) of each quad-group
#pragma unroll
    for (int rs = 0; rs < 4; ++rs)
#pragma unroll
        for (int r = 0; r < 4; ++r) {
            float m = runmax[rs][r];
            m = fmaxf(m, __shfl_xor(m, 1));
            m = fmaxf(m, __shfl_xor(m, 2));
            m = fmaxf(m, __shfl_xor(m, 4));
            m = fmaxf(m, __shfl_xor(m, 8));
            runmax[rs][r] = m;
        }

    // partial row-max for this col-group -> global [NCG][BATCH]
    if (lane16 == 0) {
#pragma unroll
        for (int rs = 0; rs < 4; ++rs)
#pragma unroll
            for (int r = 0; r < 4; ++r)
                partials[(size_t)cg * BATCH + rows0 + rs * 16 + quad * 4 + r] =
                    runmax[rs][r];
    }
}

// ---------------------------------------------------------------------------
// Kernel C: combine col-group partials, softplus, per-block sums (no atomics).
// ---------------------------------------------------------------------------
__global__ __launch_bounds__(256) void reduce_kernel(
    const float* __restrict__ partials, const float* __restrict__ pos,
    float* __restrict__ red_part)
{
    const int t = threadIdx.x;
    const int r = blockIdx.x * 256 + t;
    float fm = partials[r];
#pragma unroll
    for (int cgi = 1; cgi < NCG; ++cgi)
        fm = fmaxf(fm, partials[(size_t)cgi * BATCH + r]);
    float c = softplus_f(fm - pos[r]);
    c += __shfl_xor(c, 1);  c += __shfl_xor(c, 2);
    c += __shfl_xor(c, 4);  c += __shfl_xor(c, 8);
    c += __shfl_xor(c, 16); c += __shfl_xor(c, 32);

    __shared__ float red[4];
    if ((t & 63) == 0) red[t >> 6] = c;
    __syncthreads();
    if (t == 0)
        red_part[blockIdx.x] = red[0] + red[1] + red[2] + red[3];
}

// ---------------------------------------------------------------------------
// Kernel D: final sum of loss1_part[2048] + red_part[64] -> scalar loss.
// ---------------------------------------------------------------------------
__global__ __launch_bounds__(256) void finalize_kernel(
    const float* __restrict__ loss1_part, const float* __restrict__ red_part,
    float* __restrict__ out)
{
    const int t = threadIdx.x;
    float s = 0.0f;
#pragma unroll
    for (int i = 0; i < NPREP / 256; ++i)
        s += loss1_part[i * 256 + t];
    if (t < NRED) s += red_part[t];
    s += __shfl_xor(s, 1);  s += __shfl_xor(s, 2);
    s += __shfl_xor(s, 4);  s += __shfl_xor(s, 8);
    s += __shfl_xor(s, 16); s += __shfl_xor(s, 32);

    __shared__ float red[4];
    if ((t & 63) == 0) red[t >> 6] = s;
    __syncthreads();
    if (t == 0)
        out[0] = (red[0] + red[1] + red[2] + red[3]) * (1.0f / (2.0f * BATCH));
}

extern "C" void kernel_launch(void* const* d_in, const int* in_sizes, int n_in,
                              void* d_out, int out_size, void* d_ws, size_t ws_size,
                              hipStream_t stream)
{
    const float* q  = (const float*)d_in[0];
    const float* d  = (const float*)d_in[1];
    const float* nd = (const float*)d_in[2];
    float* out = (float*)d_out;

    char* ws = (char*)d_ws;
    float*  pos        = (float*)ws;                                 // 64 KB
    ushort* qb         = (ushort*)(ws + 65536);                      // 4 MB
    ushort* db         = (ushort*)(ws + 65536 + 4194304);            // 4 MB
    float*  partials   = (float*)(ws + 65536 + 2 * 4194304);         // 1 MB
    float*  loss1_part = (float*)(ws + 65536 + 2 * 4194304 + 1048576);     // 8 KB
    float*  red_part   = (float*)(ws + 65536 + 2 * 4194304 + 1048576 + 8192); // 256 B

    prep_kernel<<<NPREP, 256, 0, stream>>>(q, d, nd, qb, db, pos, loss1_part);
    inbatch_kernel<<<(BATCH / ROWS_PER_BLOCK) * NCG, 512, 0, stream>>>(qb, db, partials);
    reduce_kernel<<<NRED, 256, 0, stream>>>(partials, pos, red_part);
    finalize_kernel<<<1, 256, 0, stream>>>(loss1_part, red_part, out);
}

// Round 6
// 132.164 us; speedup vs baseline: 3.7028x; 3.7028x over previous
//
#include <hip/hip_runtime.h>
#include <hip/hip_bf16.h>

// BiPairwiseNegativeCELoss on MI355X.
// Inputs: q, d, nd : [16384, 128] fp32. Output: scalar fp32 loss.
// loss = 0.5 * ( mean(softplus(q.nd_row - q.d_row))
//              + mean(softplus(max_c(q_b . d_c, diag -1e6) - q_b.d_b)) )
//
// R6: R5 structure (512 blocks = 32 rg x 16 cg, 2 blocks/CU) but with
// __launch_bounds__(512, 2): R5's (512,4) capped VGPRs at 64 -> the 64-VGPR
// afrag array spilled to scratch (1.6 GB HBM traffic, 7.5x regression).
// (512,2) gives the 256-VGPR budget; body compiles to ~120 VGPR <= 128, so
// HW still co-schedules 2 blocks/CU (16 waves, 128 KB LDS).

#define BATCH 16384
#define DDIM  128
#define NWAVES 8                 // 512 threads
#define ROWS_PER_BLOCK 512       // 8 waves x 64 rows
#define COLS_PER_BLOCK 1024      // 16 col-groups
#define CHUNK_COLS 128           // 32 KB bf16 per chunk
#define NCHUNKS (COLS_PER_BLOCK / CHUNK_COLS)   // 8
#define CHUNK_USHORTS (CHUNK_COLS * DDIM)       // 16384
#define NCG (BATCH / COLS_PER_BLOCK)            // 16
#define NPREP 2048                               // prep blocks (8 rows each)
#define NRED  64                                 // reduce blocks

typedef __attribute__((ext_vector_type(8))) short bf16x8;   // 8 bf16 = 4 VGPRs
typedef __attribute__((ext_vector_type(4))) float f32x4;

__device__ __forceinline__ float softplus_f(float x) {
    return (x > 0.0f) ? x + log1pf(expf(-x)) : log1pf(expf(x));
}

__device__ __forceinline__ ushort f2bf_rne(float x) {
    unsigned u = __float_as_uint(x);
    unsigned r = (u + 0x7FFFu + ((u >> 16) & 1u)) >> 16;
    return (ushort)r;
}

#define WAITVM(n) do { \
        __builtin_amdgcn_s_waitcnt((n) | (7 << 4) | (15 << 8)); \
        asm volatile("" ::: "memory"); \
    } while (0)

// ---------------------------------------------------------------------------
// Kernel A: pairwise dots (fp32 exact), loss1 block partials, bf16 casts.
// 2048 blocks x 256 threads. Block owns 8 rows; 32 threads per row.
// ---------------------------------------------------------------------------
__global__ __launch_bounds__(256) void prep_kernel(
    const float* __restrict__ q, const float* __restrict__ d,
    const float* __restrict__ nd,
    ushort* __restrict__ qb, ushort* __restrict__ db,
    float* __restrict__ pos, float* __restrict__ loss1_part)
{
    const int t   = threadIdx.x;
    const int sub = t >> 5;                      // row 0..7 within block
    const int ln  = t & 31;                      // 32 threads per row
    const int row = blockIdx.x * 8 + sub;
    const size_t idx = (size_t)row * DDIM + ln * 4;

    float4 a = *(const float4*)(q  + idx);
    float4 b = *(const float4*)(d  + idx);
    float4 c = *(const float4*)(nd + idx);

    ushort4 o;
    o.x = f2bf_rne(a.x); o.y = f2bf_rne(a.y);
    o.z = f2bf_rne(a.z); o.w = f2bf_rne(a.w);
    *(ushort4*)(qb + idx) = o;
    ushort4 p;
    p.x = f2bf_rne(b.x); p.y = f2bf_rne(b.y);
    p.z = f2bf_rne(b.z); p.w = f2bf_rne(b.w);
    *(ushort4*)(db + idx) = p;

    float ps = a.x * b.x + a.y * b.y + a.z * b.z + a.w * b.w;
    float ns = a.x * c.x + a.y * c.y + a.z * c.z + a.w * c.w;
    ps += __shfl_xor(ps, 1); ps += __shfl_xor(ps, 2);
    ps += __shfl_xor(ps, 4); ps += __shfl_xor(ps, 8);
    ps += __shfl_xor(ps, 16);
    ns += __shfl_xor(ns, 1); ns += __shfl_xor(ns, 2);
    ns += __shfl_xor(ns, 4); ns += __shfl_xor(ns, 8);
    ns += __shfl_xor(ns, 16);

    float contrib = 0.0f;
    if (ln == 0) {
        pos[row] = ps;                     // == scores[b][b], exact fp32
        contrib = softplus_f(ns - ps);
    }
    contrib += __shfl_xor(contrib, 32);    // combine the wave's two rows

    __shared__ float red[4];
    if ((t & 63) == 0) red[t >> 6] = contrib;
    __syncthreads();
    if (t == 0)
        loss1_part[blockIdx.x] = red[0] + red[1] + red[2] + red[3];
}

// ---------------------------------------------------------------------------
// Kernel B: fused GEMM + row-max. 512 blocks x 512 threads, 2 blocks/CU.
// Block (rg = bx&31, cg = bx>>5): rows [rg*512, +512), cols [cg*1024, +1024).
// Wave w owns 64 rows (A in registers, whole K). B staged cooperatively:
// 128-col chunks, 2x32KB LDS double buffer, XOR-swizzled 16B k-segments
// (swizzle on the GLOBAL address; LDS dest of global_load_lds is lane-linear:
// LDS slot s of col c holds global segment s ^ (c&15)).
// ---------------------------------------------------------------------------
__global__ __launch_bounds__(512, 2) void inbatch_kernel(
    const ushort* __restrict__ qb, const ushort* __restrict__ db,
    float* __restrict__ partials)
{
    __shared__ ushort stg[2][CHUNK_USHORTS];   // 2 x 32 KB

    const int t      = threadIdx.x;
    const int w      = t >> 6;
    const int l      = t & 63;
    const int lane16 = l & 15;
    const int quad   = l >> 4;
    const int rg     = blockIdx.x & 31;
    const int cg     = blockIdx.x >> 5;
    const int rows0  = rg * ROWS_PER_BLOCK + w * 64;   // this wave's 64 rows
    const int col0   = cg * COLS_PER_BLOCK;

    // A fragments: lane l holds Q[rows0 + rs*16 + (l&15)][ks*32 + quad*8 + j]
    bf16x8 afrag[4][4];
#pragma unroll
    for (int rs = 0; rs < 4; ++rs)
#pragma unroll
        for (int ks = 0; ks < 4; ++ks)
            afrag[rs][ks] = *(const bf16x8*)(
                qb + (size_t)(rows0 + rs * 16 + lane16) * DDIM + ks * 32 + quad * 8);

    // staging: thread t handles 16B segments i*512 + t (i = 0..3) of each
    // chunk; seg -> col = seg>>4, LDS slot = seg&15, global kseg = slot^(col&15)
    const ushort* gsrc[4];
#pragma unroll
    for (int i = 0; i < 4; ++i) {
        int seg = i * 512 + t;
        int c   = seg >> 4;
        int s   = seg & 15;
        gsrc[i] = db + (size_t)(col0 + c) * DDIM + ((s ^ (c & 15)) * 8);
    }

    // ds_read base (ushort offsets); per-(ct,buf) selected by immediate offset
    int dsbase[4];
#pragma unroll
    for (int ks = 0; ks < 4; ++ks)
        dsbase[ks] = lane16 * DDIM + (((ks * 4 + quad) ^ lane16) * 8);

    float runmax[4][4];
#pragma unroll
    for (int rs = 0; rs < 4; ++rs)
#pragma unroll
        for (int r = 0; r < 4; ++r) runmax[rs][r] = -3.0e38f;

    // prologue: stage chunk 0 into buf 0 (LDS dest wave-uniform + lane*16B)
#pragma unroll
    for (int i = 0; i < 4; ++i)
        __builtin_amdgcn_global_load_lds(
            (const __attribute__((address_space(1))) void*)gsrc[i],
            (__attribute__((address_space(3))) void*)(&stg[0][0] + (i * 512 + w * 64) * 8),
            16, 0, 0);

    for (int ch = 0; ch < NCHUNKS; ++ch) {
        WAITVM(0);
        __syncthreads();                     // chunk ch visible; buf ch^1 free
        if (ch + 1 < NCHUNKS) {              // prefetch next chunk now; it has
#pragma unroll                               // the whole compute phase to land
            for (int i = 0; i < 4; ++i)
                __builtin_amdgcn_global_load_lds(
                    (const __attribute__((address_space(1))) void*)(gsrc[i] + (size_t)(ch + 1) * CHUNK_USHORTS),
                    (__attribute__((address_space(3))) void*)(&stg[(ch + 1) & 1][0] + (i * 512 + w * 64) * 8),
                    16, 0, 0);
        }

        const ushort* buf = &stg[ch & 1][0];
#pragma unroll
        for (int ct = 0; ct < 8; ++ct) {
            bf16x8 bfrag[4];
#pragma unroll
            for (int ks = 0; ks < 4; ++ks)
                bfrag[ks] = *(const bf16x8*)(buf + dsbase[ks] + ct * 2048);

            const int ctile = col0 + ch * CHUNK_COLS + ct * 16;
#pragma unroll
            for (int rs = 0; rs < 4; ++rs) {
                f32x4 s = {0.0f, 0.0f, 0.0f, 0.0f};
#pragma unroll
                for (int ks = 0; ks < 4; ++ks)
                    s = __builtin_amdgcn_mfma_f32_16x16x32_bf16(
                        afrag[rs][ks], bfrag[ks], s, 0, 0, 0);
                if (ctile == rows0 + rs * 16) {    // diagonal tile: -1e6
#pragma unroll
                    for (int r = 0; r < 4; ++r)
                        if (quad * 4 + r == lane16) s[r] -= 1.0e6f;
                }
#pragma unroll
                for (int r = 0; r < 4; ++r)
                    runmax[rs][r] = fmaxf(runmax[rs][r], s[r]);
            }
        }
    }

    // reduce max across the 16 lanes (cols) of each quad-group
#pragma unroll
    for (int rs = 0; rs < 4; ++rs)
#pragma unroll
        for (int r = 0; r < 4; ++r) {
            float m = runmax[rs][r];
            m = fmaxf(m, __shfl_xor(m, 1));
            m = fmaxf(m, __shfl_xor(m, 2));
            m = fmaxf(m, __shfl_xor(m, 4));
            m = fmaxf(m, __shfl_xor(m, 8));
            runmax[rs][r] = m;
        }

    // partial row-max for this col-group -> global [NCG][BATCH]
    if (lane16 == 0) {
#pragma unroll
        for (int rs = 0; rs < 4; ++rs)
#pragma unroll
            for (int r = 0; r < 4; ++r)
                partials[(size_t)cg * BATCH + rows0 + rs * 16 + quad * 4 + r] =
                    runmax[rs][r];
    }
}

// ---------------------------------------------------------------------------
// Kernel C: combine col-group partials, softplus, per-block sums (no atomics).
// ---------------------------------------------------------------------------
__global__ __launch_bounds__(256) void reduce_kernel(
    const float* __restrict__ partials, const float* __restrict__ pos,
    float* __restrict__ red_part)
{
    const int t = threadIdx.x;
    const int r = blockIdx.x * 256 + t;
    float fm = partials[r];
#pragma unroll
    for (int cgi = 1; cgi < NCG; ++cgi)
        fm = fmaxf(fm, partials[(size_t)cgi * BATCH + r]);
    float c = softplus_f(fm - pos[r]);
    c += __shfl_xor(c, 1);  c += __shfl_xor(c, 2);
    c += __shfl_xor(c, 4);  c += __shfl_xor(c, 8);
    c += __shfl_xor(c, 16); c += __shfl_xor(c, 32);

    __shared__ float red[4];
    if ((t & 63) == 0) red[t >> 6] = c;
    __syncthreads();
    if (t == 0)
        red_part[blockIdx.x] = red[0] + red[1] + red[2] + red[3];
}

// ---------------------------------------------------------------------------
// Kernel D: final sum of loss1_part[2048] + red_part[64] -> scalar loss.
// ---------------------------------------------------------------------------
__global__ __launch_bounds__(256) void finalize_kernel(
    const float* __restrict__ loss1_part, const float* __restrict__ red_part,
    float* __restrict__ out)
{
    const int t = threadIdx.x;
    float s = 0.0f;
#pragma unroll
    for (int i = 0; i < NPREP / 256; ++i)
        s += loss1_part[i * 256 + t];
    if (t < NRED) s += red_part[t];
    s += __shfl_xor(s, 1);  s += __shfl_xor(s, 2);
    s += __shfl_xor(s, 4);  s += __shfl_xor(s, 8);
    s += __shfl_xor(s, 16); s += __shfl_xor(s, 32);

    __shared__ float red[4];
    if ((t & 63) == 0) red[t >> 6] = s;
    __syncthreads();
    if (t == 0)
        out[0] = (red[0] + red[1] + red[2] + red[3]) * (1.0f / (2.0f * BATCH));
}

extern "C" void kernel_launch(void* const* d_in, const int* in_sizes, int n_in,
                              void* d_out, int out_size, void* d_ws, size_t ws_size,
                              hipStream_t stream)
{
    const float* q  = (const float*)d_in[0];
    const float* d  = (const float*)d_in[1];
    const float* nd = (const float*)d_in[2];
    float* out = (float*)d_out;

    char* ws = (char*)d_ws;
    float*  pos        = (float*)ws;                                 // 64 KB
    ushort* qb         = (ushort*)(ws + 65536);                      // 4 MB
    ushort* db         = (ushort*)(ws + 65536 + 4194304);            // 4 MB
    float*  partials   = (float*)(ws + 65536 + 2 * 4194304);         // 1 MB
    float*  loss1_part = (float*)(ws + 65536 + 2 * 4194304 + 1048576);     // 8 KB
    float*  red_part   = (float*)(ws + 65536 + 2 * 4194304 + 1048576 + 8192); // 256 B

    prep_kernel<<<NPREP, 256, 0, stream>>>(q, d, nd, qb, db, pos, loss1_part);
    inbatch_kernel<<<(BATCH / ROWS_PER_BLOCK) * NCG, 512, 0, stream>>>(qb, db, partials);
    reduce_kernel<<<NRED, 256, 0, stream>>>(partials, pos, red_part);
    finalize_kernel<<<1, 256, 0, stream>>>(loss1_part, red_part, out);
}

// Round 7
// 129.467 us; speedup vs baseline: 3.7799x; 1.0208x over previous
//
#include <hip/hip_runtime.h>
#include <hip/hip_bf16.h>

// BiPairwiseNegativeCELoss on MI355X.
// Inputs: q, d, nd : [16384, 128] fp32. Output: scalar fp32 loss.
// loss = 0.5 * ( mean(softplus(q.nd_row - q.d_row))
//              + mean(softplus(max_c(q_b . d_c, diag -1e6) - q_b.d_b)) )
//
// R7: two independent 4-wave blocks per CU instead of one 8-wave block.
// Per-wave regs (~130 incl AGPRs) cap HW at 2 waves/SIMD; an 8-wave block
// then owns the CU and self-stalls at every chunk barrier (R6: MfmaUtil 46%).
// 256-thread blocks (4 waves x 64 rows, 1024 cols, 64-col chunks, 32 KB LDS)
// keep the same per-wave tile but let 2 desynchronized blocks co-reside:
// one block's vmcnt/barrier drain overlaps the other's MFMA burst.

#define BATCH 16384
#define DDIM  128
#define NWAVES 4                 // 256 threads
#define ROWS_PER_BLOCK 256       // 4 waves x 64 rows
#define COLS_PER_BLOCK 1024      // 16 col-groups
#define CHUNK_COLS 64            // 16 KB bf16 per chunk buffer
#define NCHUNKS (COLS_PER_BLOCK / CHUNK_COLS)   // 16
#define CHUNK_USHORTS (CHUNK_COLS * DDIM)       // 8192
#define NCG (BATCH / COLS_PER_BLOCK)            // 16
#define NRG (BATCH / ROWS_PER_BLOCK)            // 64
#define NPREP 2048                               // prep blocks (8 rows each)
#define NRED  64                                 // reduce blocks

typedef __attribute__((ext_vector_type(8))) short bf16x8;   // 8 bf16 = 4 VGPRs
typedef __attribute__((ext_vector_type(4))) float f32x4;

__device__ __forceinline__ float softplus_f(float x) {
    return (x > 0.0f) ? x + log1pf(expf(-x)) : log1pf(expf(x));
}

__device__ __forceinline__ ushort f2bf_rne(float x) {
    unsigned u = __float_as_uint(x);
    unsigned r = (u + 0x7FFFu + ((u >> 16) & 1u)) >> 16;
    return (ushort)r;
}

#define WAITVM(n) do { \
        __builtin_amdgcn_s_waitcnt((n) | (7 << 4) | (15 << 8)); \
        asm volatile("" ::: "memory"); \
    } while (0)

// ---------------------------------------------------------------------------
// Kernel A: pairwise dots (fp32 exact), loss1 block partials, bf16 casts.
// 2048 blocks x 256 threads. Block owns 8 rows; 32 threads per row.
// ---------------------------------------------------------------------------
__global__ __launch_bounds__(256) void prep_kernel(
    const float* __restrict__ q, const float* __restrict__ d,
    const float* __restrict__ nd,
    ushort* __restrict__ qb, ushort* __restrict__ db,
    float* __restrict__ pos, float* __restrict__ loss1_part)
{
    const int t   = threadIdx.x;
    const int sub = t >> 5;                      // row 0..7 within block
    const int ln  = t & 31;                      // 32 threads per row
    const int row = blockIdx.x * 8 + sub;
    const size_t idx = (size_t)row * DDIM + ln * 4;

    float4 a = *(const float4*)(q  + idx);
    float4 b = *(const float4*)(d  + idx);
    float4 c = *(const float4*)(nd + idx);

    ushort4 o;
    o.x = f2bf_rne(a.x); o.y = f2bf_rne(a.y);
    o.z = f2bf_rne(a.z); o.w = f2bf_rne(a.w);
    *(ushort4*)(qb + idx) = o;
    ushort4 p;
    p.x = f2bf_rne(b.x); p.y = f2bf_rne(b.y);
    p.z = f2bf_rne(b.z); p.w = f2bf_rne(b.w);
    *(ushort4*)(db + idx) = p;

    float ps = a.x * b.x + a.y * b.y + a.z * b.z + a.w * b.w;
    float ns = a.x * c.x + a.y * c.y + a.z * c.z + a.w * c.w;
    ps += __shfl_xor(ps, 1); ps += __shfl_xor(ps, 2);
    ps += __shfl_xor(ps, 4); ps += __shfl_xor(ps, 8);
    ps += __shfl_xor(ps, 16);
    ns += __shfl_xor(ns, 1); ns += __shfl_xor(ns, 2);
    ns += __shfl_xor(ns, 4); ns += __shfl_xor(ns, 8);
    ns += __shfl_xor(ns, 16);

    float contrib = 0.0f;
    if (ln == 0) {
        pos[row] = ps;                     // == scores[b][b], exact fp32
        contrib = softplus_f(ns - ps);
    }
    contrib += __shfl_xor(contrib, 32);    // combine the wave's two rows

    __shared__ float red[4];
    if ((t & 63) == 0) red[t >> 6] = contrib;
    __syncthreads();
    if (t == 0)
        loss1_part[blockIdx.x] = red[0] + red[1] + red[2] + red[3];
}

// ---------------------------------------------------------------------------
// Kernel B: fused GEMM + row-max. 1024 blocks x 256 threads, 2 blocks/CU
// co-resident (32 KB LDS, ~130 regs -> 2 waves/SIMD: one from each block).
// Block (rg = bx&63, cg = bx>>6): rows [rg*256, +256), cols [cg*1024, +1024).
// Wave w owns 64 rows (A in registers, whole K). B staged cooperatively:
// 64-col chunks, 2x16KB LDS double buffer, XOR-swizzled 16B k-segments
// (swizzle on the GLOBAL address; LDS dest of global_load_lds is lane-linear:
// LDS slot s of col c holds global segment s ^ (c&15)).
// ---------------------------------------------------------------------------
__global__ __launch_bounds__(256, 2) void inbatch_kernel(
    const ushort* __restrict__ qb, const ushort* __restrict__ db,
    float* __restrict__ partials)
{
    __shared__ ushort stg[2][CHUNK_USHORTS];   // 2 x 16 KB

    const int t      = threadIdx.x;
    const int w      = t >> 6;
    const int l      = t & 63;
    const int lane16 = l & 15;
    const int quad   = l >> 4;
    const int rg     = blockIdx.x & 63;
    const int cg     = blockIdx.x >> 6;
    const int rows0  = rg * ROWS_PER_BLOCK + w * 64;   // this wave's 64 rows
    const int col0   = cg * COLS_PER_BLOCK;

    // A fragments: lane l holds Q[rows0 + rs*16 + (l&15)][ks*32 + quad*8 + j]
    bf16x8 afrag[4][4];
#pragma unroll
    for (int rs = 0; rs < 4; ++rs)
#pragma unroll
        for (int ks = 0; ks < 4; ++ks)
            afrag[rs][ks] = *(const bf16x8*)(
                qb + (size_t)(rows0 + rs * 16 + lane16) * DDIM + ks * 32 + quad * 8);

    // staging: thread t handles 16B segments i*256 + t (i = 0..3) per chunk;
    // col = i*16 + (t>>4), LDS slot = t&15, global kseg = (t&15)^((t>>4)&15)
    const ushort* gsrc[4];
#pragma unroll
    for (int i = 0; i < 4; ++i) {
        int c = i * 16 + (t >> 4);
        gsrc[i] = db + (size_t)(col0 + c) * DDIM + (((t & 15) ^ ((t >> 4) & 15)) * 8);
    }

    // ds_read base (ushort offsets); per-(ct,buf) selected by immediate offset
    int dsbase[4];
#pragma unroll
    for (int ks = 0; ks < 4; ++ks)
        dsbase[ks] = lane16 * DDIM + (((ks * 4 + quad) ^ lane16) * 8);

    float runmax[4][4];
#pragma unroll
    for (int rs = 0; rs < 4; ++rs)
#pragma unroll
        for (int r = 0; r < 4; ++r) runmax[rs][r] = -3.0e38f;

    // prologue: stage chunk 0 into buf 0 (LDS dest wave-uniform + lane*16B)
#pragma unroll
    for (int i = 0; i < 4; ++i)
        __builtin_amdgcn_global_load_lds(
            (const __attribute__((address_space(1))) void*)gsrc[i],
            (__attribute__((address_space(3))) void*)(&stg[0][0] + (i * 256 + w * 64) * 8),
            16, 0, 0);

    for (int ch = 0; ch < NCHUNKS; ++ch) {
        WAITVM(0);
        __syncthreads();                     // chunk ch visible; buf ch^1 free
        if (ch + 1 < NCHUNKS) {              // prefetch next chunk now; it has
#pragma unroll                               // the whole compute phase to land
            for (int i = 0; i < 4; ++i)
                __builtin_amdgcn_global_load_lds(
                    (const __attribute__((address_space(1))) void*)(gsrc[i] + (size_t)(ch + 1) * CHUNK_USHORTS),
                    (__attribute__((address_space(3))) void*)(&stg[(ch + 1) & 1][0] + (i * 256 + w * 64) * 8),
                    16, 0, 0);
        }

        const ushort* buf = &stg[ch & 1][0];
#pragma unroll
        for (int ct = 0; ct < 4; ++ct) {
            bf16x8 bfrag[4];
#pragma unroll
            for (int ks = 0; ks < 4; ++ks)
                bfrag[ks] = *(const bf16x8*)(buf + dsbase[ks] + ct * 2048);

            const int ctile = col0 + ch * CHUNK_COLS + ct * 16;
#pragma unroll
            for (int rs = 0; rs < 4; ++rs) {
                f32x4 s = {0.0f, 0.0f, 0.0f, 0.0f};
#pragma unroll
                for (int ks = 0; ks < 4; ++ks)
                    s = __builtin_amdgcn_mfma_f32_16x16x32_bf16(
                        afrag[rs][ks], bfrag[ks], s, 0, 0, 0);
                if (ctile == rows0 + rs * 16) {    // diagonal tile: -1e6
#pragma unroll
                    for (int r = 0; r < 4; ++r)
                        if (quad * 4 + r == lane16) s[r] -= 1.0e6f;
                }
#pragma unroll
                for (int r = 0; r < 4; ++r)
                    runmax[rs][r] = fmaxf(runmax[rs][r], s[r]);
            }
        }
    }

    // reduce max across the 16 lanes (cols) of each quad-group
#pragma unroll
    for (int rs = 0; rs < 4; ++rs)
#pragma unroll
        for (int r = 0; r < 4; ++r) {
            float m = runmax[rs][r];
            m = fmaxf(m, __shfl_xor(m, 1));
            m = fmaxf(m, __shfl_xor(m, 2));
            m = fmaxf(m, __shfl_xor(m, 4));
            m = fmaxf(m, __shfl_xor(m, 8));
            runmax[rs][r] = m;
        }

    // partial row-max for this col-group -> global [NCG][BATCH]
    if (lane16 == 0) {
#pragma unroll
        for (int rs = 0; rs < 4; ++rs)
#pragma unroll
            for (int r = 0; r < 4; ++r)
                partials[(size_t)cg * BATCH + rows0 + rs * 16 + quad * 4 + r] =
                    runmax[rs][r];
    }
}

// ---------------------------------------------------------------------------
// Kernel C: combine col-group partials, softplus, per-block sums (no atomics).
// ---------------------------------------------------------------------------
__global__ __launch_bounds__(256) void reduce_kernel(
    const float* __restrict__ partials, const float* __restrict__ pos,
    float* __restrict__ red_part)
{
    const int t = threadIdx.x;
    const int r = blockIdx.x * 256 + t;
    float fm = partials[r];
#pragma unroll
    for (int cgi = 1; cgi < NCG; ++cgi)
        fm = fmaxf(fm, partials[(size_t)cgi * BATCH + r]);
    float c = softplus_f(fm - pos[r]);
    c += __shfl_xor(c, 1);  c += __shfl_xor(c, 2);
    c += __shfl_xor(c, 4);  c += __shfl_xor(c, 8);
    c += __shfl_xor(c, 16); c += __shfl_xor(c, 32);

    __shared__ float red[4];
    if ((t & 63) == 0) red[t >> 6] = c;
    __syncthreads();
    if (t == 0)
        red_part[blockIdx.x] = red[0] + red[1] + red[2] + red[3];
}

// ---------------------------------------------------------------------------
// Kernel D: final sum of loss1_part[2048] + red_part[64] -> scalar loss.
// ---------------------------------------------------------------------------
__global__ __launch_bounds__(256) void finalize_kernel(
    const float* __restrict__ loss1_part, const float* __restrict__ red_part,
    float* __restrict__ out)
{
    const int t = threadIdx.x;
    float s = 0.0f;
#pragma unroll
    for (int i = 0; i < NPREP / 256; ++i)
        s += loss1_part[i * 256 + t];
    if (t < NRED) s += red_part[t];
    s += __shfl_xor(s, 1);  s += __shfl_xor(s, 2);
    s += __shfl_xor(s, 4);  s += __shfl_xor(s, 8);
    s += __shfl_xor(s, 16); s += __shfl_xor(s, 32);

    __shared__ float red[4];
    if ((t & 63) == 0) red[t >> 6] = s;
    __syncthreads();
    if (t == 0)
        out[0] = (red[0] + red[1] + red[2] + red[3]) * (1.0f / (2.0f * BATCH));
}

extern "C" void kernel_launch(void* const* d_in, const int* in_sizes, int n_in,
                              void* d_out, int out_size, void* d_ws, size_t ws_size,
                              hipStream_t stream)
{
    const float* q  = (const float*)d_in[0];
    const float* d  = (const float*)d_in[1];
    const float* nd = (const float*)d_in[2];
    float* out = (float*)d_out;

    char* ws = (char*)d_ws;
    float*  pos        = (float*)ws;                                 // 64 KB
    ushort* qb         = (ushort*)(ws + 65536);                      // 4 MB
    ushort* db         = (ushort*)(ws + 65536 + 4194304);            // 4 MB
    float*  partials   = (float*)(ws + 65536 + 2 * 4194304);         // 1 MB
    float*  loss1_part = (float*)(ws + 65536 + 2 * 4194304 + 1048576);     // 8 KB
    float*  red_part   = (float*)(ws + 65536 + 2 * 4194304 + 1048576 + 8192); // 256 B

    prep_kernel<<<NPREP, 256, 0, stream>>>(q, d, nd, qb, db, pos, loss1_part);
    inbatch_kernel<<<NRG * NCG, 256, 0, stream>>>(qb, db, partials);
    reduce_kernel<<<NRED, 256, 0, stream>>>(partials, pos, red_part);
    finalize_kernel<<<1, 256, 0, stream>>>(loss1_part, red_part, out);
}

// Round 8
// 129.430 us; speedup vs baseline: 3.7810x; 1.0003x over previous
//
#include <hip/hip_runtime.h>
#include <hip/hip_bf16.h>

// BiPairwiseNegativeCELoss on MI355X.
// Inputs: q, d, nd : [16384, 128] fp32. Output: scalar fp32 loss.
// loss = 0.5 * ( mean(softplus(q.nd_row - q.d_row))
//              + mean(softplus(max_c(q_b . d_c, diag -1e6) - q_b.d_b)) )
//
// R8: intra-wave software pipelining. R4/R6/R7 all pin at MfmaUtil~47%:
// per-CU accounting shows wall = MFMA(2483cyc) + LDS(1536cyc) per chunk-round
// -- the pipes serialize because each wave's bfrag ds_reads sit directly
// before their MFMA use. Fix: register-double-buffer B fragments (load tile
// ct+1 under tile ct's MFMA burst) + hoist accumulator zero-init.
// Same shapes/layouts/grid as R7 (verified absmax 0.0).

#define BATCH 16384
#define DDIM  128
#define NWAVES 4                 // 256 threads
#define ROWS_PER_BLOCK 256       // 4 waves x 64 rows
#define COLS_PER_BLOCK 1024      // 16 col-groups
#define CHUNK_COLS 64            // 16 KB bf16 per chunk buffer
#define NCHUNKS (COLS_PER_BLOCK / CHUNK_COLS)   // 16
#define CHUNK_USHORTS (CHUNK_COLS * DDIM)       // 8192
#define NCG (BATCH / COLS_PER_BLOCK)            // 16
#define NRG (BATCH / ROWS_PER_BLOCK)            // 64
#define NPREP 2048                               // prep blocks (8 rows each)
#define NRED  64                                 // reduce blocks

typedef __attribute__((ext_vector_type(8))) short bf16x8;   // 8 bf16 = 4 VGPRs
typedef __attribute__((ext_vector_type(4))) float f32x4;

__device__ __forceinline__ float softplus_f(float x) {
    return (x > 0.0f) ? x + log1pf(expf(-x)) : log1pf(expf(x));
}

__device__ __forceinline__ ushort f2bf_rne(float x) {
    unsigned u = __float_as_uint(x);
    unsigned r = (u + 0x7FFFu + ((u >> 16) & 1u)) >> 16;
    return (ushort)r;
}

#define WAITVM(n) do { \
        __builtin_amdgcn_s_waitcnt((n) | (7 << 4) | (15 << 8)); \
        asm volatile("" ::: "memory"); \
    } while (0)

// ---------------------------------------------------------------------------
// Kernel A: pairwise dots (fp32 exact), loss1 block partials, bf16 casts.
// 2048 blocks x 256 threads. Block owns 8 rows; 32 threads per row.
// ---------------------------------------------------------------------------
__global__ __launch_bounds__(256) void prep_kernel(
    const float* __restrict__ q, const float* __restrict__ d,
    const float* __restrict__ nd,
    ushort* __restrict__ qb, ushort* __restrict__ db,
    float* __restrict__ pos, float* __restrict__ loss1_part)
{
    const int t   = threadIdx.x;
    const int sub = t >> 5;                      // row 0..7 within block
    const int ln  = t & 31;                      // 32 threads per row
    const int row = blockIdx.x * 8 + sub;
    const size_t idx = (size_t)row * DDIM + ln * 4;

    float4 a = *(const float4*)(q  + idx);
    float4 b = *(const float4*)(d  + idx);
    float4 c = *(const float4*)(nd + idx);

    ushort4 o;
    o.x = f2bf_rne(a.x); o.y = f2bf_rne(a.y);
    o.z = f2bf_rne(a.z); o.w = f2bf_rne(a.w);
    *(ushort4*)(qb + idx) = o;
    ushort4 p;
    p.x = f2bf_rne(b.x); p.y = f2bf_rne(b.y);
    p.z = f2bf_rne(b.z); p.w = f2bf_rne(b.w);
    *(ushort4*)(db + idx) = p;

    float ps = a.x * b.x + a.y * b.y + a.z * b.z + a.w * b.w;
    float ns = a.x * c.x + a.y * c.y + a.z * c.z + a.w * c.w;
    ps += __shfl_xor(ps, 1); ps += __shfl_xor(ps, 2);
    ps += __shfl_xor(ps, 4); ps += __shfl_xor(ps, 8);
    ps += __shfl_xor(ps, 16);
    ns += __shfl_xor(ns, 1); ns += __shfl_xor(ns, 2);
    ns += __shfl_xor(ns, 4); ns += __shfl_xor(ns, 8);
    ns += __shfl_xor(ns, 16);

    float contrib = 0.0f;
    if (ln == 0) {
        pos[row] = ps;                     // == scores[b][b], exact fp32
        contrib = softplus_f(ns - ps);
    }
    contrib += __shfl_xor(contrib, 32);    // combine the wave's two rows

    __shared__ float red[4];
    if ((t & 63) == 0) red[t >> 6] = contrib;
    __syncthreads();
    if (t == 0)
        loss1_part[blockIdx.x] = red[0] + red[1] + red[2] + red[3];
}

// ---------------------------------------------------------------------------
// Kernel B: fused GEMM + row-max. 1024 blocks x 256 threads, 2 blocks/CU.
// Block (rg = bx&63, cg = bx>>6): rows [rg*256, +256), cols [cg*1024, +1024).
// Wave w owns 64 rows (A in registers, whole K). B staged cooperatively:
// 64-col chunks, 2x16KB LDS double buffer, XOR-swizzled 16B k-segments.
// NEW in R8: B-fragment register double-buffer -- tile ct+1's ds_reads are
// issued before tile ct's MFMA burst, overlapping LDS latency/throughput
// with the matrix pipe inside each wave. Accumulator init hoisted (zinit).
// ---------------------------------------------------------------------------
__global__ __launch_bounds__(256, 2) void inbatch_kernel(
    const ushort* __restrict__ qb, const ushort* __restrict__ db,
    float* __restrict__ partials)
{
    __shared__ ushort stg[2][CHUNK_USHORTS];   // 2 x 16 KB

    const int t      = threadIdx.x;
    const int w      = t >> 6;
    const int l      = t & 63;
    const int lane16 = l & 15;
    const int quad   = l >> 4;
    const int rg     = blockIdx.x & 63;
    const int cg     = blockIdx.x >> 6;
    const int rows0  = rg * ROWS_PER_BLOCK + w * 64;   // this wave's 64 rows
    const int col0   = cg * COLS_PER_BLOCK;

    // A fragments: lane l holds Q[rows0 + rs*16 + (l&15)][ks*32 + quad*8 + j]
    bf16x8 afrag[4][4];
#pragma unroll
    for (int rs = 0; rs < 4; ++rs)
#pragma unroll
        for (int ks = 0; ks < 4; ++ks)
            afrag[rs][ks] = *(const bf16x8*)(
                qb + (size_t)(rows0 + rs * 16 + lane16) * DDIM + ks * 32 + quad * 8);

    // staging: thread t handles 16B segments i*256 + t (i = 0..3) per chunk;
    // col = i*16 + (t>>4), LDS slot = t&15, global kseg = (t&15)^((t>>4)&15)
    const ushort* gsrc[4];
#pragma unroll
    for (int i = 0; i < 4; ++i) {
        int c = i * 16 + (t >> 4);
        gsrc[i] = db + (size_t)(col0 + c) * DDIM + (((t & 15) ^ ((t >> 4) & 15)) * 8);
    }

    // ds_read base (ushort offsets); per-(ct,buf) selected by immediate offset
    int dsbase[4];
#pragma unroll
    for (int ks = 0; ks < 4; ++ks)
        dsbase[ks] = lane16 * DDIM + (((ks * 4 + quad) ^ lane16) * 8);

    const f32x4 zinit = {0.0f, 0.0f, 0.0f, 0.0f};   // hoisted acc init

    float runmax[4][4];
#pragma unroll
    for (int rs = 0; rs < 4; ++rs)
#pragma unroll
        for (int r = 0; r < 4; ++r) runmax[rs][r] = -3.0e38f;

    // prologue: stage chunk 0 into buf 0 (LDS dest wave-uniform + lane*16B)
#pragma unroll
    for (int i = 0; i < 4; ++i)
        __builtin_amdgcn_global_load_lds(
            (const __attribute__((address_space(1))) void*)gsrc[i],
            (__attribute__((address_space(3))) void*)(&stg[0][0] + (i * 256 + w * 64) * 8),
            16, 0, 0);

    for (int ch = 0; ch < NCHUNKS; ++ch) {
        WAITVM(0);
        __syncthreads();                     // chunk ch visible; buf ch^1 free
        if (ch + 1 < NCHUNKS) {              // prefetch next chunk now; it has
#pragma unroll                               // the whole compute phase to land
            for (int i = 0; i < 4; ++i)
                __builtin_amdgcn_global_load_lds(
                    (const __attribute__((address_space(1))) void*)(gsrc[i] + (size_t)(ch + 1) * CHUNK_USHORTS),
                    (__attribute__((address_space(3))) void*)(&stg[(ch + 1) & 1][0] + (i * 256 + w * 64) * 8),
                    16, 0, 0);
        }

        const ushort* buf = &stg[ch & 1][0];

        // software pipeline: bcur = tile ct, bnxt = tile ct+1 (in flight
        // under ct's MFMA burst)
        bf16x8 bcur[4];
#pragma unroll
        for (int ks = 0; ks < 4; ++ks)
            bcur[ks] = *(const bf16x8*)(buf + dsbase[ks]);

#pragma unroll
        for (int ct = 0; ct < 4; ++ct) {
            bf16x8 bnxt[4];
            if (ct < 3) {
#pragma unroll
                for (int ks = 0; ks < 4; ++ks)
                    bnxt[ks] = *(const bf16x8*)(buf + dsbase[ks] + (ct + 1) * 2048);
            }

            const int ctile = col0 + ch * CHUNK_COLS + ct * 16;
#pragma unroll
            for (int rs = 0; rs < 4; ++rs) {
                f32x4 s = __builtin_amdgcn_mfma_f32_16x16x32_bf16(
                    afrag[rs][0], bcur[0], zinit, 0, 0, 0);
#pragma unroll
                for (int ks = 1; ks < 4; ++ks)
                    s = __builtin_amdgcn_mfma_f32_16x16x32_bf16(
                        afrag[rs][ks], bcur[ks], s, 0, 0, 0);
                if (ctile == rows0 + rs * 16) {    // diagonal tile: -1e6
#pragma unroll
                    for (int r = 0; r < 4; ++r)
                        if (quad * 4 + r == lane16) s[r] -= 1.0e6f;
                }
#pragma unroll
                for (int r = 0; r < 4; ++r)
                    runmax[rs][r] = fmaxf(runmax[rs][r], s[r]);
            }

            if (ct < 3) {
#pragma unroll
                for (int ks = 0; ks < 4; ++ks) bcur[ks] = bnxt[ks];
            }
        }
    }

    // reduce max across the 16 lanes (cols) of each quad-group
#pragma unroll
    for (int rs = 0; rs < 4; ++rs)
#pragma unroll
        for (int r = 0; r < 4; ++r) {
            float m = runmax[rs][r];
            m = fmaxf(m, __shfl_xor(m, 1));
            m = fmaxf(m, __shfl_xor(m, 2));
            m = fmaxf(m, __shfl_xor(m, 4));
            m = fmaxf(m, __shfl_xor(m, 8));
            runmax[rs][r] = m;
        }

    // partial row-max for this col-group -> global [NCG][BATCH]
    if (lane16 == 0) {
#pragma unroll
        for (int rs = 0; rs < 4; ++rs)
#pragma unroll
            for (int r = 0; r < 4; ++r)
                partials[(size_t)cg * BATCH + rows0 + rs * 16 + quad * 4 + r] =
                    runmax[rs][r];
    }
}

// ---------------------------------------------------------------------------
// Kernel C: combine col-group partials, softplus, per-block sums (no atomics).
// ---------------------------------------------------------------------------
__global__ __launch_bounds__(256) void reduce_kernel(
    const float* __restrict__ partials, const float* __restrict__ pos,
    float* __restrict__ red_part)
{
    const int t = threadIdx.x;
    const int r = blockIdx.x * 256 + t;
    float fm = partials[r];
#pragma unroll
    for (int cgi = 1; cgi < NCG; ++cgi)
        fm = fmaxf(fm, partials[(size_t)cgi * BATCH + r]);
    float c = softplus_f(fm - pos[r]);
    c += __shfl_xor(c, 1);  c += __shfl_xor(c, 2);
    c += __shfl_xor(c, 4);  c += __shfl_xor(c, 8);
    c += __shfl_xor(c, 16); c += __shfl_xor(c, 32);

    __shared__ float red[4];
    if ((t & 63) == 0) red[t >> 6] = c;
    __syncthreads();
    if (t == 0)
        red_part[blockIdx.x] = red[0] + red[1] + red[2] + red[3];
}

// ---------------------------------------------------------------------------
// Kernel D: final sum of loss1_part[2048] + red_part[64] -> scalar loss.
// ---------------------------------------------------------------------------
__global__ __launch_bounds__(256) void finalize_kernel(
    const float* __restrict__ loss1_part, const float* __restrict__ red_part,
    float* __restrict__ out)
{
    const int t = threadIdx.x;
    float s = 0.0f;
#pragma unroll
    for (int i = 0; i < NPREP / 256; ++i)
        s += loss1_part[i * 256 + t];
    if (t < NRED) s += red_part[t];
    s += __shfl_xor(s, 1);  s += __shfl_xor(s, 2);
    s += __shfl_xor(s, 4);  s += __shfl_xor(s, 8);
    s += __shfl_xor(s, 16); s += __shfl_xor(s, 32);

    __shared__ float red[4];
    if ((t & 63) == 0) red[t >> 6] = s;
    __syncthreads();
    if (t == 0)
        out[0] = (red[0] + red[1] + red[2] + red[3]) * (1.0f / (2.0f * BATCH));
}

extern "C" void kernel_launch(void* const* d_in, const int* in_sizes, int n_in,
                              void* d_out, int out_size, void* d_ws, size_t ws_size,
                              hipStream_t stream)
{
    const float* q  = (const float*)d_in[0];
    const float* d  = (const float*)d_in[1];
    const float* nd = (const float*)d_in[2];
    float* out = (float*)d_out;

    char* ws = (char*)d_ws;
    float*  pos        = (float*)ws;                                 // 64 KB
    ushort* qb         = (ushort*)(ws + 65536);                      // 4 MB
    ushort* db         = (ushort*)(ws + 65536 + 4194304);            // 4 MB
    float*  partials   = (float*)(ws + 65536 + 2 * 4194304);         // 1 MB
    float*  loss1_part = (float*)(ws + 65536 + 2 * 4194304 + 1048576);     // 8 KB
    float*  red_part   = (float*)(ws + 65536 + 2 * 4194304 + 1048576 + 8192); // 256 B

    prep_kernel<<<NPREP, 256, 0, stream>>>(q, d, nd, qb, db, pos, loss1_part);
    inbatch_kernel<<<NRG * NCG, 256, 0, stream>>>(qb, db, partials);
    reduce_kernel<<<NRED, 256, 0, stream>>>(partials, pos, red_part);
    finalize_kernel<<<1, 256, 0, stream>>>(loss1_part, red_part, out);
}